// Round 1
// baseline (1065.407 us; speedup 1.0000x reference)
//
#include <hip/hip_runtime.h>

#define NN 100000
#define NE 3200000
#define INCH 200
#define HID 64
#define NG 500

// ---------------- edge degree + count ----------------
__global__ void k_edge_deg_count(const int* __restrict__ ei, const float* __restrict__ attr,
                                 float* __restrict__ deg, int* __restrict__ cnti) {
  int stride = gridDim.x * blockDim.x;
  for (int e = blockIdx.x * blockDim.x + threadIdx.x; e < NE; e += stride) {
    int c = ei[NE + e];
    float w = fabsf(attr[e]);
    atomicAdd(&deg[c], w);
    atomicAdd(&cnti[c], 1);
  }
}

__global__ void k_dinv(const float* __restrict__ deg, float* __restrict__ dinv) {
  int i = blockIdx.x * blockDim.x + threadIdx.x;
  if (i < NN) dinv[i] = 1.0f / sqrtf(deg[i] + 1.0f);
}

// ---------------- scan (3-kernel, 1024 elems/block) ----------------
__global__ void k_scan1(const int* __restrict__ in, int* __restrict__ incl, int* __restrict__ bsums) {
  __shared__ int wsum[4];
  int tid = threadIdx.x, b = blockIdx.x;
  int base = b * 1024 + tid * 4;
  int v0 = 0, v1 = 0, v2 = 0, v3 = 0;
  if (base + 3 < NN) {
    int4 q = *(const int4*)(in + base);
    v0 = q.x; v1 = q.y; v2 = q.z; v3 = q.w;
  } else {
    if (base     < NN) v0 = in[base];
    if (base + 1 < NN) v1 = in[base + 1];
    if (base + 2 < NN) v2 = in[base + 2];
  }
  int s0 = v0, s1 = s0 + v1, s2 = s1 + v2, s3 = s2 + v3;
  int t = s3;
  int lane = tid & 63, wid = tid >> 6;
  #pragma unroll
  for (int d = 1; d < 64; d <<= 1) { int u = __shfl_up(t, d); if (lane >= d) t += u; }
  if (lane == 63) wsum[wid] = t;
  __syncthreads();
  int woff = 0;
  for (int w = 0; w < wid; ++w) woff += wsum[w];
  int texcl = t - s3 + woff;
  if (base < NN) {
    int o0 = texcl + s0, o1 = texcl + s1, o2 = texcl + s2, o3 = texcl + s3;
    if (base + 3 < NN) {
      *(int4*)(incl + base) = make_int4(o0, o1, o2, o3);
    } else {
      incl[base] = o0;
      if (base + 1 < NN) incl[base + 1] = o1;
      if (base + 2 < NN) incl[base + 2] = o2;
    }
  }
  if (tid == 255) bsums[b] = texcl + s3;
}

__global__ void k_scan2(const int* __restrict__ bsums, int* __restrict__ boffs, int nb) {
  __shared__ int wsum[4];
  int tid = threadIdx.x;
  int v = (tid < nb) ? bsums[tid] : 0;
  int t = v;
  int lane = tid & 63, wid = tid >> 6;
  #pragma unroll
  for (int d = 1; d < 64; d <<= 1) { int u = __shfl_up(t, d); if (lane >= d) t += u; }
  if (lane == 63) wsum[wid] = t;
  __syncthreads();
  int woff = 0;
  for (int w = 0; w < wid; ++w) woff += wsum[w];
  if (tid < nb) boffs[tid] = woff + t - v;
}

__global__ void k_scan3(const int* __restrict__ incl, const int* __restrict__ boffs,
                        int* __restrict__ offs, int* __restrict__ cursor) {
  int i = blockIdx.x * blockDim.x + threadIdx.x;
  if (i < NN) {
    int v = incl[i] + boffs[i >> 10];
    offs[i + 1] = v;
    if (i + 1 < NN) cursor[i + 1] = v;
    if (i == 0) { offs[0] = 0; cursor[0] = 0; }
  }
}

// ---------------- scatter into CSR ----------------
__global__ void k_scatter(const int* __restrict__ ei, const float* __restrict__ attr,
                          const float* __restrict__ dinv, int* __restrict__ cursor,
                          int* __restrict__ erow, float* __restrict__ enorm) {
  int stride = gridDim.x * blockDim.x;
  for (int e = blockIdx.x * blockDim.x + threadIdx.x; e < NE; e += stride) {
    int r = ei[e], c = ei[NE + e];
    float w = fabsf(attr[e]);
    int p = atomicAdd(&cursor[c], 1);
    erow[p] = r;
    enorm[p] = dinv[r] * w * dinv[c];
  }
}

// ---------------- fp32 GEMM: C[M][64] = A[M][K] @ B[K][64] ----------------
__global__ __launch_bounds__(256) void k_gemm(const float* __restrict__ A,
                                              const float* __restrict__ B,
                                              float* __restrict__ C, int M, int K) {
  __shared__ float As[8][256];
  __shared__ float Bs[8][64];
  int tid = threadIdx.x;
  int ng = tid >> 3, cg = tid & 7;
  int nbase = blockIdx.x * 256;
  float acc[8][8];
  #pragma unroll
  for (int i = 0; i < 8; i++)
    #pragma unroll
    for (int j = 0; j < 8; j++) acc[i][j] = 0.f;

  for (int k0 = 0; k0 < K; k0 += 8) {
    int n = nbase + tid;
    int nc = n < M ? n : M - 1;
    float4 a0 = *(const float4*)(A + (size_t)nc * K + k0);
    float4 a1 = *(const float4*)(A + (size_t)nc * K + k0 + 4);
    float2 bv = ((const float2*)(B + (size_t)k0 * 64))[tid];
    __syncthreads();
    As[0][tid] = a0.x; As[1][tid] = a0.y; As[2][tid] = a0.z; As[3][tid] = a0.w;
    As[4][tid] = a1.x; As[5][tid] = a1.y; As[6][tid] = a1.z; As[7][tid] = a1.w;
    ((float2*)Bs)[tid] = bv;
    __syncthreads();
    #pragma unroll
    for (int k = 0; k < 8; k++) {
      float a[8], bb[8];
      *(float4*)(a)      = *(const float4*)&As[k][ng * 8];
      *(float4*)(a + 4)  = *(const float4*)&As[k][ng * 8 + 4];
      *(float4*)(bb)     = *(const float4*)&Bs[k][cg * 8];
      *(float4*)(bb + 4) = *(const float4*)&Bs[k][cg * 8 + 4];
      #pragma unroll
      for (int i = 0; i < 8; i++)
        #pragma unroll
        for (int j = 0; j < 8; j++) acc[i][j] += a[i] * bb[j];
    }
  }
  #pragma unroll
  for (int i = 0; i < 8; i++) {
    int n = nbase + ng * 8 + i;
    if (n < M) {
      *(float4*)(C + (size_t)n * 64 + cg * 8)     = make_float4(acc[i][0], acc[i][1], acc[i][2], acc[i][3]);
      *(float4*)(C + (size_t)n * 64 + cg * 8 + 4) = make_float4(acc[i][4], acc[i][5], acc[i][6], acc[i][7]);
    }
  }
}

// ---------------- CSR aggregation + self-loop + bias + relu ----------------
__global__ void k_agg(const float* __restrict__ h, const int* __restrict__ offs,
                      const int* __restrict__ erow, const float* __restrict__ enorm,
                      const float* __restrict__ dinv, const float* __restrict__ bias,
                      float* __restrict__ out) {
  int node = blockIdx.x * 4 + (threadIdx.x >> 6);
  int lane = threadIdx.x & 63;
  if (node >= NN) return;
  int e0 = offs[node], e1 = offs[node + 1];
  float acc = 0.f;
  int e = e0;
  for (; e + 4 <= e1; e += 4) {
    int r0 = erow[e], r1 = erow[e + 1], r2 = erow[e + 2], r3 = erow[e + 3];
    float w0 = enorm[e], w1 = enorm[e + 1], w2 = enorm[e + 2], w3 = enorm[e + 3];
    acc += w0 * h[(size_t)r0 * 64 + lane];
    acc += w1 * h[(size_t)r1 * 64 + lane];
    acc += w2 * h[(size_t)r2 * 64 + lane];
    acc += w3 * h[(size_t)r3 * 64 + lane];
  }
  for (; e < e1; ++e) acc += enorm[e] * h[(size_t)erow[e] * 64 + lane];
  float dv = dinv[node];
  acc += dv * dv * h[(size_t)node * 64 + lane] + bias[lane];
  out[(size_t)node * 64 + lane] = fmaxf(acc, 0.f);
}

// ---------------- pooling (batch sorted -> run-accumulate) ----------------
__global__ void k_pool(const float* __restrict__ h, const int* __restrict__ batch,
                       float* __restrict__ pooled) {
  int c = threadIdx.x & 63, j = threadIdx.x >> 6;
  int base = blockIdx.x * 64 + j * 16;
  float acc = 0.f;
  int curg = -1;
  for (int i = 0; i < 16; i++) {
    int n = base + i;
    if (n >= NN) break;
    int g = batch[n];
    if (g != curg) {
      if (curg >= 0) atomicAdd(&pooled[curg * 64 + c], acc);
      curg = g; acc = 0.f;
    }
    acc += h[(size_t)n * 64 + c];
  }
  if (curg >= 0) atomicAdd(&pooled[curg * 64 + c], acc);
}

__global__ void k_gcnt(const int* __restrict__ batch, int* __restrict__ gcnt) {
  int i = blockIdx.x * blockDim.x + threadIdx.x;
  if (i < NN) atomicAdd(&gcnt[batch[i]], 1);
}

// ---------------- MLP head: one block per graph ----------------
__global__ __launch_bounds__(256) void k_mlp(const float* __restrict__ pooled,
                                             const int* __restrict__ gcnt,
                                             const float* __restrict__ L1, const float* __restrict__ c1,
                                             const float* __restrict__ L2, const float* __restrict__ c2,
                                             float* __restrict__ out) {
  __shared__ float m[64];
  __shared__ float xf[200];
  __shared__ float red[8];
  int g = blockIdx.x, tid = threadIdx.x;
  if (tid < 64) {
    float cnt = fmaxf((float)gcnt[g], 1.f);
    m[tid] = pooled[g * 64 + tid] / cnt;
  }
  __syncthreads();
  if (tid < 200) {
    float a = c1[tid];
    #pragma unroll
    for (int k = 0; k < 64; k++) a += m[k] * L1[k * 200 + tid];
    xf[tid] = fmaxf(a, 0.f);
  }
  __syncthreads();
  float p0 = 0.f, p1 = 0.f;
  if (tid < 200) {
    float v = xf[tid];
    p0 = v * L2[tid * 2];
    p1 = v * L2[tid * 2 + 1];
  }
  #pragma unroll
  for (int d = 32; d > 0; d >>= 1) { p0 += __shfl_down(p0, d); p1 += __shfl_down(p1, d); }
  int lane = tid & 63, wid = tid >> 6;
  if (lane == 0) { red[wid * 2] = p0; red[wid * 2 + 1] = p1; }
  __syncthreads();
  if (tid == 0) {
    out[g * 2 + 0] = red[0] + red[2] + red[4] + red[6] + c2[0];
    out[g * 2 + 1] = red[1] + red[3] + red[5] + red[7] + c2[1];
  }
}

// ---------------- launch ----------------
extern "C" void kernel_launch(void* const* d_in, const int* in_sizes, int n_in,
                              void* d_out, int out_size, void* d_ws, size_t ws_size,
                              hipStream_t stream) {
  (void)in_sizes; (void)n_in; (void)out_size; (void)ws_size;
  const float* x    = (const float*)d_in[0];
  const int*   ei   = (const int*)d_in[1];
  const float* attr = (const float*)d_in[2];
  const int*   batch= (const int*)d_in[3];
  const float* W1   = (const float*)d_in[4];
  const float* b1   = (const float*)d_in[5];
  const float* W2   = (const float*)d_in[6];
  const float* b2   = (const float*)d_in[7];
  const float* L1   = (const float*)d_in[8];
  const float* c1   = (const float*)d_in[9];
  const float* L2   = (const float*)d_in[10];
  const float* c2   = (const float*)d_in[11];
  float* out = (float*)d_out;

  char* p = (char*)d_ws;
  auto alloc = [&](size_t bytes) -> void* {
    void* r = (void*)p;
    p += (bytes + 511) & ~(size_t)511;
    return r;
  };
  float* deg    = (float*)alloc((size_t)NN * 4);
  float* dinv   = (float*)alloc((size_t)NN * 4);
  int*   cnti   = (int*)alloc((size_t)NN * 4);
  int*   incl   = (int*)alloc((size_t)NN * 4);
  int*   bsums  = (int*)alloc(1024 * 4);
  int*   boffs  = (int*)alloc(1024 * 4);
  int*   offs   = (int*)alloc((size_t)(NN + 1) * 4);
  int*   cursor = (int*)alloc((size_t)NN * 4);
  int*   erow   = (int*)alloc((size_t)NE * 4);
  float* enorm  = (float*)alloc((size_t)NE * 4);
  float* h1     = (float*)alloc((size_t)NN * 64 * 4);
  float* h2     = (float*)alloc((size_t)NN * 64 * 4);
  float* pooled = (float*)alloc((size_t)NG * 64 * 4);
  int*   gcnt   = (int*)alloc((size_t)NG * 4);

  hipMemsetAsync(deg, 0, (size_t)NN * 4, stream);
  hipMemsetAsync(cnti, 0, (size_t)NN * 4, stream);
  hipMemsetAsync(pooled, 0, (size_t)NG * 64 * 4, stream);
  hipMemsetAsync(gcnt, 0, (size_t)NG * 4, stream);

  // CSR build
  k_edge_deg_count<<<2048, 256, 0, stream>>>(ei, attr, deg, cnti);
  k_dinv<<<(NN + 255) / 256, 256, 0, stream>>>(deg, dinv);
  int nb = (NN + 1023) / 1024;
  k_scan1<<<nb, 256, 0, stream>>>(cnti, incl, bsums);
  k_scan2<<<1, 256, 0, stream>>>(bsums, boffs, nb);
  k_scan3<<<(NN + 255) / 256, 256, 0, stream>>>(incl, boffs, offs, cursor);
  k_scatter<<<2048, 256, 0, stream>>>(ei, attr, dinv, cursor, erow, enorm);

  // layer 1
  k_gemm<<<(NN + 255) / 256, 256, 0, stream>>>(x, W1, h1, NN, INCH);
  k_agg<<<NN / 4, 256, 0, stream>>>(h1, offs, erow, enorm, dinv, b1, h2);
  // layer 2
  k_gemm<<<(NN + 255) / 256, 256, 0, stream>>>(h2, W2, h1, NN, HID);
  k_agg<<<NN / 4, 256, 0, stream>>>(h1, offs, erow, enorm, dinv, b2, h2);

  // pool + head
  k_pool<<<(NN + 63) / 64, 256, 0, stream>>>(h2, batch, pooled);
  k_gcnt<<<(NN + 255) / 256, 256, 0, stream>>>(batch, gcnt);
  k_mlp<<<NG, 256, 0, stream>>>(pooled, gcnt, L1, c1, L2, c2, out);
}

// Round 2
// 1000.581 us; speedup vs baseline: 1.0648x; 1.0648x over previous
//
#include <hip/hip_runtime.h>

#define NN 100000
#define NE 3200000
#define INCH 200
#define HID 64
#define NG 500

// ---------------- linked-list build: 1 atomicExch per edge ----------------
__global__ void k_build(const int* __restrict__ ei, int* __restrict__ head,
                        int* __restrict__ nxt) {
  int stride = gridDim.x * blockDim.x;
  for (int e = blockIdx.x * blockDim.x + threadIdx.x; e < NE; e += stride) {
    int c = ei[NE + e];
    int old = atomicExch(&head[c], e);
    nxt[e] = old;
  }
}

// ---------------- walk 1: count + weighted degree (no atomics) ----------------
__global__ void k_walk1(const int* __restrict__ head, const int* __restrict__ nxt,
                        const float* __restrict__ attr,
                        int* __restrict__ cnti, float* __restrict__ deg) {
  int n = blockIdx.x * blockDim.x + threadIdx.x;
  if (n >= NN) return;
  int e = head[n];
  int c = 0;
  float d = 0.f;
  while (e >= 0) {
    c++;
    d += fabsf(attr[e]);
    e = nxt[e];
  }
  cnti[n] = c;
  deg[n] = d;
}

__global__ void k_dinv(const float* __restrict__ deg, float* __restrict__ dinv) {
  int i = blockIdx.x * blockDim.x + threadIdx.x;
  if (i < NN) dinv[i] = 1.0f / sqrtf(deg[i] + 1.0f);
}

// ---------------- scan (3-kernel, 1024 elems/block) ----------------
__global__ void k_scan1(const int* __restrict__ in, int* __restrict__ incl, int* __restrict__ bsums) {
  __shared__ int wsum[4];
  int tid = threadIdx.x, b = blockIdx.x;
  int base = b * 1024 + tid * 4;
  int v0 = 0, v1 = 0, v2 = 0, v3 = 0;
  if (base + 3 < NN) {
    int4 q = *(const int4*)(in + base);
    v0 = q.x; v1 = q.y; v2 = q.z; v3 = q.w;
  } else {
    if (base     < NN) v0 = in[base];
    if (base + 1 < NN) v1 = in[base + 1];
    if (base + 2 < NN) v2 = in[base + 2];
  }
  int s0 = v0, s1 = s0 + v1, s2 = s1 + v2, s3 = s2 + v3;
  int t = s3;
  int lane = tid & 63, wid = tid >> 6;
  #pragma unroll
  for (int d = 1; d < 64; d <<= 1) { int u = __shfl_up(t, d); if (lane >= d) t += u; }
  if (lane == 63) wsum[wid] = t;
  __syncthreads();
  int woff = 0;
  for (int w = 0; w < wid; ++w) woff += wsum[w];
  int texcl = t - s3 + woff;
  if (base < NN) {
    int o0 = texcl + s0, o1 = texcl + s1, o2 = texcl + s2, o3 = texcl + s3;
    if (base + 3 < NN) {
      *(int4*)(incl + base) = make_int4(o0, o1, o2, o3);
    } else {
      incl[base] = o0;
      if (base + 1 < NN) incl[base + 1] = o1;
      if (base + 2 < NN) incl[base + 2] = o2;
    }
  }
  if (tid == 255) bsums[b] = texcl + s3;
}

__global__ void k_scan2(const int* __restrict__ bsums, int* __restrict__ boffs, int nb) {
  __shared__ int wsum[4];
  int tid = threadIdx.x;
  int v = (tid < nb) ? bsums[tid] : 0;
  int t = v;
  int lane = tid & 63, wid = tid >> 6;
  #pragma unroll
  for (int d = 1; d < 64; d <<= 1) { int u = __shfl_up(t, d); if (lane >= d) t += u; }
  if (lane == 63) wsum[wid] = t;
  __syncthreads();
  int woff = 0;
  for (int w = 0; w < wid; ++w) woff += wsum[w];
  if (tid < nb) boffs[tid] = woff + t - v;
}

__global__ void k_scan3(const int* __restrict__ incl, const int* __restrict__ boffs,
                        int* __restrict__ offs) {
  int i = blockIdx.x * blockDim.x + threadIdx.x;
  if (i < NN) {
    int v = incl[i] + boffs[i >> 10];
    offs[i + 1] = v;
    if (i == 0) offs[0] = 0;
  }
}

// ---------------- walk 2: emit array CSR (erow, enorm) ----------------
__global__ void k_walk2(const int* __restrict__ head, const int* __restrict__ nxt,
                        const int* __restrict__ ei, const float* __restrict__ attr,
                        const float* __restrict__ dinv, const int* __restrict__ offs,
                        int* __restrict__ erow, float* __restrict__ enorm) {
  int n = blockIdx.x * blockDim.x + threadIdx.x;
  if (n >= NN) return;
  int e = head[n];
  int p = offs[n];
  float dc = dinv[n];
  while (e >= 0) {
    int r = ei[e];
    erow[p] = r;
    enorm[p] = dinv[r] * fabsf(attr[e]) * dc;
    p++;
    e = nxt[e];
  }
}

// ---------------- fp32 GEMM: C[M][64] = A[M][K] @ B[K][64] ----------------
__global__ __launch_bounds__(256) void k_gemm(const float* __restrict__ A,
                                              const float* __restrict__ B,
                                              float* __restrict__ C, int M, int K) {
  __shared__ float As[8][256];
  __shared__ float Bs[8][64];
  int tid = threadIdx.x;
  int ng = tid >> 3, cg = tid & 7;
  int nbase = blockIdx.x * 256;
  float acc[8][8];
  #pragma unroll
  for (int i = 0; i < 8; i++)
    #pragma unroll
    for (int j = 0; j < 8; j++) acc[i][j] = 0.f;

  for (int k0 = 0; k0 < K; k0 += 8) {
    int n = nbase + tid;
    int nc = n < M ? n : M - 1;
    float4 a0 = *(const float4*)(A + (size_t)nc * K + k0);
    float4 a1 = *(const float4*)(A + (size_t)nc * K + k0 + 4);
    float2 bv = ((const float2*)(B + (size_t)k0 * 64))[tid];
    __syncthreads();
    As[0][tid] = a0.x; As[1][tid] = a0.y; As[2][tid] = a0.z; As[3][tid] = a0.w;
    As[4][tid] = a1.x; As[5][tid] = a1.y; As[6][tid] = a1.z; As[7][tid] = a1.w;
    ((float2*)Bs)[tid] = bv;
    __syncthreads();
    #pragma unroll
    for (int k = 0; k < 8; k++) {
      float a[8], bb[8];
      *(float4*)(a)      = *(const float4*)&As[k][ng * 8];
      *(float4*)(a + 4)  = *(const float4*)&As[k][ng * 8 + 4];
      *(float4*)(bb)     = *(const float4*)&Bs[k][cg * 8];
      *(float4*)(bb + 4) = *(const float4*)&Bs[k][cg * 8 + 4];
      #pragma unroll
      for (int i = 0; i < 8; i++)
        #pragma unroll
        for (int j = 0; j < 8; j++) acc[i][j] += a[i] * bb[j];
    }
  }
  #pragma unroll
  for (int i = 0; i < 8; i++) {
    int n = nbase + ng * 8 + i;
    if (n < M) {
      *(float4*)(C + (size_t)n * 64 + cg * 8)     = make_float4(acc[i][0], acc[i][1], acc[i][2], acc[i][3]);
      *(float4*)(C + (size_t)n * 64 + cg * 8 + 4) = make_float4(acc[i][4], acc[i][5], acc[i][6], acc[i][7]);
    }
  }
}

// ---------------- CSR aggregation + self-loop + bias + relu ----------------
__global__ void k_agg(const float* __restrict__ h, const int* __restrict__ offs,
                      const int* __restrict__ erow, const float* __restrict__ enorm,
                      const float* __restrict__ dinv, const float* __restrict__ bias,
                      float* __restrict__ out) {
  int node = blockIdx.x * 4 + (threadIdx.x >> 6);
  int lane = threadIdx.x & 63;
  if (node >= NN) return;
  int e0 = offs[node], e1 = offs[node + 1];
  float acc = 0.f;
  int e = e0;
  for (; e + 4 <= e1; e += 4) {
    int r0 = erow[e], r1 = erow[e + 1], r2 = erow[e + 2], r3 = erow[e + 3];
    float w0 = enorm[e], w1 = enorm[e + 1], w2 = enorm[e + 2], w3 = enorm[e + 3];
    acc += w0 * h[(size_t)r0 * 64 + lane];
    acc += w1 * h[(size_t)r1 * 64 + lane];
    acc += w2 * h[(size_t)r2 * 64 + lane];
    acc += w3 * h[(size_t)r3 * 64 + lane];
  }
  for (; e < e1; ++e) acc += enorm[e] * h[(size_t)erow[e] * 64 + lane];
  float dv = dinv[node];
  acc += dv * dv * h[(size_t)node * 64 + lane] + bias[lane];
  out[(size_t)node * 64 + lane] = fmaxf(acc, 0.f);
}

// ---------------- pooling (batch sorted -> run-accumulate) ----------------
__global__ void k_pool(const float* __restrict__ h, const int* __restrict__ batch,
                       float* __restrict__ pooled) {
  int c = threadIdx.x & 63, j = threadIdx.x >> 6;
  int base = blockIdx.x * 64 + j * 16;
  float acc = 0.f;
  int curg = -1;
  for (int i = 0; i < 16; i++) {
    int n = base + i;
    if (n >= NN) break;
    int g = batch[n];
    if (g != curg) {
      if (curg >= 0) atomicAdd(&pooled[curg * 64 + c], acc);
      curg = g; acc = 0.f;
    }
    acc += h[(size_t)n * 64 + c];
  }
  if (curg >= 0) atomicAdd(&pooled[curg * 64 + c], acc);
}

__global__ void k_gcnt(const int* __restrict__ batch, int* __restrict__ gcnt) {
  int i = blockIdx.x * blockDim.x + threadIdx.x;
  if (i < NN) atomicAdd(&gcnt[batch[i]], 1);
}

// ---------------- MLP head: one block per graph ----------------
__global__ __launch_bounds__(256) void k_mlp(const float* __restrict__ pooled,
                                             const int* __restrict__ gcnt,
                                             const float* __restrict__ L1, const float* __restrict__ c1,
                                             const float* __restrict__ L2, const float* __restrict__ c2,
                                             float* __restrict__ out) {
  __shared__ float m[64];
  __shared__ float xf[200];
  __shared__ float red[8];
  int g = blockIdx.x, tid = threadIdx.x;
  if (tid < 64) {
    float cnt = fmaxf((float)gcnt[g], 1.f);
    m[tid] = pooled[g * 64 + tid] / cnt;
  }
  __syncthreads();
  if (tid < 200) {
    float a = c1[tid];
    #pragma unroll
    for (int k = 0; k < 64; k++) a += m[k] * L1[k * 200 + tid];
    xf[tid] = fmaxf(a, 0.f);
  }
  __syncthreads();
  float p0 = 0.f, p1 = 0.f;
  if (tid < 200) {
    float v = xf[tid];
    p0 = v * L2[tid * 2];
    p1 = v * L2[tid * 2 + 1];
  }
  #pragma unroll
  for (int d = 32; d > 0; d >>= 1) { p0 += __shfl_down(p0, d); p1 += __shfl_down(p1, d); }
  int lane = tid & 63, wid = tid >> 6;
  if (lane == 0) { red[wid * 2] = p0; red[wid * 2 + 1] = p1; }
  __syncthreads();
  if (tid == 0) {
    out[g * 2 + 0] = red[0] + red[2] + red[4] + red[6] + c2[0];
    out[g * 2 + 1] = red[1] + red[3] + red[5] + red[7] + c2[1];
  }
}

// ---------------- launch ----------------
extern "C" void kernel_launch(void* const* d_in, const int* in_sizes, int n_in,
                              void* d_out, int out_size, void* d_ws, size_t ws_size,
                              hipStream_t stream) {
  (void)in_sizes; (void)n_in; (void)out_size; (void)ws_size;
  const float* x    = (const float*)d_in[0];
  const int*   ei   = (const int*)d_in[1];
  const float* attr = (const float*)d_in[2];
  const int*   batch= (const int*)d_in[3];
  const float* W1   = (const float*)d_in[4];
  const float* b1   = (const float*)d_in[5];
  const float* W2   = (const float*)d_in[6];
  const float* b2   = (const float*)d_in[7];
  const float* L1   = (const float*)d_in[8];
  const float* c1   = (const float*)d_in[9];
  const float* L2   = (const float*)d_in[10];
  const float* c2   = (const float*)d_in[11];
  float* out = (float*)d_out;

  char* p = (char*)d_ws;
  auto alloc = [&](size_t bytes) -> void* {
    void* r = (void*)p;
    p += (bytes + 511) & ~(size_t)511;
    return r;
  };
  int*   head   = (int*)alloc((size_t)NN * 4);
  int*   nxt    = (int*)alloc((size_t)NE * 4);
  float* deg    = (float*)alloc((size_t)NN * 4);
  float* dinv   = (float*)alloc((size_t)NN * 4);
  int*   cnti   = (int*)alloc((size_t)NN * 4);
  int*   incl   = (int*)alloc((size_t)NN * 4);
  int*   bsums  = (int*)alloc(1024 * 4);
  int*   boffs  = (int*)alloc(1024 * 4);
  int*   offs   = (int*)alloc((size_t)(NN + 1) * 4);
  int*   erow   = (int*)alloc((size_t)NE * 4);
  float* enorm  = (float*)alloc((size_t)NE * 4);
  float* h1     = (float*)alloc((size_t)NN * 64 * 4);
  float* h2     = (float*)alloc((size_t)NN * 64 * 4);
  float* pooled = (float*)alloc((size_t)NG * 64 * 4);
  int*   gcnt   = (int*)alloc((size_t)NG * 4);

  hipMemsetAsync(head, 0xFF, (size_t)NN * 4, stream);   // head = -1
  hipMemsetAsync(pooled, 0, (size_t)NG * 64 * 4, stream);
  hipMemsetAsync(gcnt, 0, (size_t)NG * 4, stream);

  // CSR build via linked lists (1 atomicExch per edge)
  k_build<<<2048, 256, 0, stream>>>(ei, head, nxt);
  k_walk1<<<(NN + 255) / 256, 256, 0, stream>>>(head, nxt, attr, cnti, deg);
  k_dinv<<<(NN + 255) / 256, 256, 0, stream>>>(deg, dinv);
  int nb = (NN + 1023) / 1024;
  k_scan1<<<nb, 256, 0, stream>>>(cnti, incl, bsums);
  k_scan2<<<1, 256, 0, stream>>>(bsums, boffs, nb);
  k_scan3<<<(NN + 255) / 256, 256, 0, stream>>>(incl, boffs, offs);
  k_walk2<<<(NN + 255) / 256, 256, 0, stream>>>(head, nxt, ei, attr, dinv, offs, erow, enorm);

  // layer 1
  k_gemm<<<(NN + 255) / 256, 256, 0, stream>>>(x, W1, h1, NN, INCH);
  k_agg<<<NN / 4, 256, 0, stream>>>(h1, offs, erow, enorm, dinv, b1, h2);
  // layer 2
  k_gemm<<<(NN + 255) / 256, 256, 0, stream>>>(h2, W2, h1, NN, HID);
  k_agg<<<NN / 4, 256, 0, stream>>>(h1, offs, erow, enorm, dinv, b2, h2);

  // pool + head
  k_pool<<<(NN + 63) / 64, 256, 0, stream>>>(h2, batch, pooled);
  k_gcnt<<<(NN + 255) / 256, 256, 0, stream>>>(batch, gcnt);
  k_mlp<<<NG, 256, 0, stream>>>(pooled, gcnt, L1, c1, L2, c2, out);
}